// Round 7
// baseline (122.833 us; speedup 1.0000x reference)
//
#include <hip/hip_runtime.h>
#include <math.h>

#define HIDDEN 256
#define CHUNK 8
#define WAVES 8

typedef float fx4 __attribute__((ext_vector_type(4)));

// Kernel 1: build segment boundary array starts[0..G] from sorted batch ids.
__global__ __launch_bounds__(256) void seg_starts_kernel(
    const int* __restrict__ batch, int* __restrict__ starts, int N, int G) {
  int i = blockIdx.x * blockDim.x + threadIdx.x;
  if (i >= N) return;
  int b = batch[i];
  int prev = (i == 0) ? -1 : batch[i - 1];
  for (int g = prev + 1; g <= b; ++g) starts[g] = i;
  if (i == N - 1) {
    for (int g = b + 1; g <= G; ++g) starts[g] = N;
  }
}

// Kernel 2: block = 8 waves = 1 graph; wave q takes nodes
// [start + q*total/8, start + (q+1)*total/8) via masked 8-node chunks
// (padded lanes: clamped duplicate row loads -> L1 hits, s=-inf, mult=0).
// 8 online-softmax states merged via LDS by wave 0.
__global__ __launch_bounds__(512) void pool_kernel(
    const float* __restrict__ h, const float* __restrict__ node_mult,
    const float* __restrict__ pressure, const float* __restrict__ attn_weight,
    const float* __restrict__ attn_bias, const float* __restrict__ W_pressure,
    const int* __restrict__ starts, float* __restrict__ out, int G) {
  const int q    = threadIdx.x >> 6;   // wave 0..7
  const int lane = threadIdx.x & 63;
  const int g = blockIdx.x;

  __shared__ float s_m[WAVES - 1], s_d[WAVES - 1], s_t[WAVES - 1];
  __shared__ fx4 s_attn[WAVES - 1][64], s_mean[WAVES - 1][64],
      s_max[WAVES - 1][64];

  const int start = starts[g];
  const int end   = starts[g + 1];
  const int total = end - start;

  const fx4 w4 = *reinterpret_cast<const fx4*>(attn_weight + 4 * lane);
  const float bias = attn_bias[0];

  fx4 attn  = (fx4)(0.f);
  fx4 meanv = (fx4)(0.f);
  fx4 maxv  = (fx4)(-INFINITY);
  float m = -INFINITY;
  float denom = 0.f;
  float tmult = 0.f;

  const int n_lo = start + (q * total) / WAVES;
  const int n_hi = start + ((q + 1) * total) / WAVES;

  for (int i = n_lo; i < n_hi; i += CHUNK) {
    const int cnt = (n_hi - i < CHUNK) ? (n_hi - i) : CHUNK;  // 1..8
    fx4 hv[CHUNK];
    float mult[CHUNK];
#pragma unroll
    for (int j = 0; j < CHUNK; ++j) {
      const int idx = i + ((j < cnt) ? j : cnt - 1);  // clamped, in-bounds
      hv[j] = __builtin_nontemporal_load(
          reinterpret_cast<const fx4*>(h + (size_t)idx * HIDDEN + 4 * lane));
      mult[j] = (j < cnt) ? node_mult[i + j] : 0.f;
    }

    float p[CHUNK];
#pragma unroll
    for (int j = 0; j < CHUNK; ++j)
      p[j] = hv[j].x * w4.x + hv[j].y * w4.y + hv[j].z * w4.z + hv[j].w * w4.w;

#pragma unroll
    for (int off = 32; off >= 1; off >>= 1) {
#pragma unroll
      for (int j = 0; j < CHUNK; ++j) p[j] += __shfl_xor(p[j], off, 64);
    }

    float s[CHUNK];
#pragma unroll
    for (int j = 0; j < CHUNK; ++j)
      s[j] = (j < cnt) ? (p[j] + bias + __logf(fmaxf(mult[j], 1.f)))
                       : -INFINITY;

    float cmax = s[0];
#pragma unroll
    for (int j = 1; j < CHUNK; ++j) cmax = fmaxf(cmax, s[j]);

    if (cmax > m) {
      const float scale = __expf(m - cmax);  // m=-inf -> 0
      denom *= scale;
      attn *= scale;
      m = cmax;
    }

#pragma unroll
    for (int j = 0; j < CHUNK; ++j) {
      const float e = __expf(s[j] - m);  // padded: exp(-inf - finite) = 0
      denom += e;
      attn += hv[j] * e;
      meanv += hv[j] * mult[j];          // padded: mult = 0
      const bool v = (j < cnt);
      maxv.x = fmaxf(maxv.x, v ? hv[j].x : -INFINITY);
      maxv.y = fmaxf(maxv.y, v ? hv[j].y : -INFINITY);
      maxv.z = fmaxf(maxv.z, v ? hv[j].z : -INFINITY);
      maxv.w = fmaxf(maxv.w, v ? hv[j].w : -INFINITY);
      tmult += mult[j];
    }
  }

  // waves 1..7 publish; wave 0 merges and writes output
  if (q > 0) {
    if (lane == 0) { s_m[q - 1] = m; s_d[q - 1] = denom; s_t[q - 1] = tmult; }
    s_attn[q - 1][lane] = attn;
    s_mean[q - 1][lane] = meanv;
    s_max[q - 1][lane]  = maxv;
  }
  __syncthreads();

  if (q == 0) {
    float M = m, D = denom, T = tmult;
    fx4 A = attn, Me = meanv, Mx = maxv;
#pragma unroll
    for (int k = 0; k < WAVES - 1; ++k) {
      const float mk = s_m[k];
      const float Mn = fmaxf(M, mk);
      const float sc0 = (M  == -INFINITY) ? 0.f : __expf(M  - Mn);
      const float sck = (mk == -INFINITY) ? 0.f : __expf(mk - Mn);
      D = D * sc0 + s_d[k] * sck;
      A = A * sc0 + s_attn[k][lane] * sck;
      M = Mn;
      Me += s_mean[k][lane];
      const fx4 mxk = s_max[k][lane];
      Mx.x = fmaxf(Mx.x, mxk.x);  Mx.y = fmaxf(Mx.y, mxk.y);
      Mx.z = fmaxf(Mx.z, mxk.z);  Mx.w = fmaxf(Mx.w, mxk.w);
      T += s_t[k];
    }

    const float inv_tm  = 1.f / fmaxf(T, 1e-8f);
    const float inv_den = (D > 0.f) ? 1.f / D : 0.f;
    const float p_norm  = pressure[g] * (1.f / 300.f);
    const fx4 wp4 = *reinterpret_cast<const fx4*>(W_pressure + 4 * lane);

    fx4 res = 0.5f * (Me * inv_tm + A * inv_den) + p_norm * wp4;

    float* outg = out + (size_t)g * (2 * HIDDEN);
    *reinterpret_cast<fx4*>(outg + 4 * lane) = res;
    *reinterpret_cast<fx4*>(outg + HIDDEN + 4 * lane) = Mx;
  }
}

extern "C" void kernel_launch(void* const* d_in, const int* in_sizes, int n_in,
                              void* d_out, int out_size, void* d_ws, size_t ws_size,
                              hipStream_t stream) {
  const float* h           = (const float*)d_in[0];
  const float* node_mult   = (const float*)d_in[1];
  const float* pressure    = (const float*)d_in[2];
  const float* attn_weight = (const float*)d_in[3];
  const float* attn_bias   = (const float*)d_in[4];
  const float* W_pressure  = (const float*)d_in[5];
  const int*   batch       = (const int*)d_in[6];

  const int N = in_sizes[1];
  const int G = in_sizes[2];

  int* starts = (int*)d_ws;
  float* out = (float*)d_out;

  seg_starts_kernel<<<(N + 255) / 256, 256, 0, stream>>>(batch, starts, N, G);
  pool_kernel<<<G, 512, 0, stream>>>(h, node_mult, pressure,
                                     attn_weight, attn_bias,
                                     W_pressure, starts, out, G);
}